// Round 14
// baseline (16.536 us; speedup 1.0000x reference)
//
#include <hip/hip_runtime.h>
#include <math.h>

#define B_SZ   512
#define M_MIX  32
#define D_DIM  1024
#define T_MAX  4096
#define P3M    96            // 3 * M_MIX
#define RPB    4             // batch rows per block
#define NBLK   (B_SZ / RPB)  // 128 blocks
#define NTHR   512
#define KQ     16            // in-block k-split
#define KCH    (D_DIM / KQ)  // 64
#define JQ     (P3M / 4)     // 24 j-quads
#define NGEMM  (JQ * KQ)     // 384 GEMM threads (waves 0-5)

typedef float vf4 __attribute__((ext_vector_type(4)));

// ---------------------------------------------------------------------------
// Single-node fused kernel, zero cross-block deps, no workspace.
// 128 blocks x 512 threads, RPB=4 rows/block. Halves W L2 redundancy vs
// RPB=2 (49 MB vs 98 MB -> B-phase L2 floor 1.4 us) while keeping r11's
// vectorized GEMM (the r10 RPB=4 test regressed with SCALAR loads + 1024 thr
// -- confounded; this isolates RPB with the fast B).
//   A) stage q[4][1024] in LDS (float4, 2/thread)
//   B) WAVE-SPLIT: waves 0-5 (384 thr): thread = (j-quad, kq); 64 vf4 W
//      loads, 4 vf4 accumulators (16 FMA/load). waves 6-7: NT zero-fill of
//      the block's 4 output rows (no L2 allocate; hidden under B).
//   C) reduce 16 partials + transform (384 thr: 4 rows x 96)
//   D) per-row window min/max (4 waves, mixtures duplicated)
//   E) phi in 2 passes of 2 rows (same body/maths as r11 -> bit-identical
//      per-row results); NT stores only i-blocks in [0, gmax].
// ---------------------------------------------------------------------------
__global__ __launch_bounds__(NTHR) void fused_kernel(
    const float* __restrict__ query,
    const float* __restrict__ prev_kappa,
    const float* __restrict__ W,
    const float* __restrict__ bias,
    const int* __restrict__ seqlen,
    float* __restrict__ out)
{
    __shared__ float sQ[RPB][D_DIM];      // 16 KB
    __shared__ float sP[KQ][RPB][P3M];    // 24 KB partials
    __shared__ float sA[RPB][M_MIX];      // alpha
    __shared__ float sC[RPB][M_MIX];      // -beta * log2(e)
    __shared__ float sK[RPB][M_MIX];      // kappa
    __shared__ float sR[RPB][M_MIX];      // half-width sqrt(37/beta)
    __shared__ float sRange[RPB][2];
    __shared__ float sRed[RPB][4];
    __shared__ int   sL[RPB];

    const int tid = threadIdx.x;
    const int b0  = blockIdx.x * RPB;

    // ---- A: stage q (512 thr x two float4) ----
    #pragma unroll
    for (int i = 0; i < 2; ++i) {
        const int id = tid + i * NTHR;    // 0..1023 over 4 rows x 256 vf4
        const int r  = id >> 8;
        const int c  = id & 255;
        reinterpret_cast<float4*>(&sQ[r][0])[c] =
            reinterpret_cast<const float4*>(query + (size_t)(b0 + r) * D_DIM)[c];
    }
    if (tid < RPB) sL[tid] = seqlen[b0 + tid];
    __syncthreads();

    // ---- B: wave-split GEMM (waves 0-5) || NT zero-fill (waves 6-7) ----
    if (tid < NGEMM) {
        const int jq = tid % JQ;
        const int kq = tid / JQ;
        const float* Wp = W + (size_t)(kq * KCH) * P3M + jq * 4;
        const float* q0 = &sQ[0][kq * KCH];
        const float* q1 = &sQ[1][kq * KCH];
        const float* q2 = &sQ[2][kq * KCH];
        const float* q3 = &sQ[3][kq * KCH];
        vf4 a0 = {0.f, 0.f, 0.f, 0.f};
        vf4 a1 = {0.f, 0.f, 0.f, 0.f};
        vf4 a2 = {0.f, 0.f, 0.f, 0.f};
        vf4 a3 = {0.f, 0.f, 0.f, 0.f};
        #pragma unroll 8
        for (int d = 0; d < KCH; ++d) {
            const vf4 w = *reinterpret_cast<const vf4*>(Wp + (size_t)d * P3M);
            a0 += w * q0[d];
            a1 += w * q1[d];
            a2 += w * q2[d];
            a3 += w * q3[d];
        }
        *reinterpret_cast<vf4*>(&sP[kq][0][jq * 4]) = a0;
        *reinterpret_cast<vf4*>(&sP[kq][1][jq * 4]) = a1;
        *reinterpret_cast<vf4*>(&sP[kq][2][jq * 4]) = a2;
        *reinterpret_cast<vf4*>(&sP[kq][3][jq * 4]) = a3;
    } else {
        // 128 threads zero the block's 4 output rows: 4096 vf4, 32 each (NT)
        const int zb = tid - NGEMM;       // 0..127
        vf4* oz = reinterpret_cast<vf4*>(out + (size_t)b0 * T_MAX);
        const vf4 z = {0.f, 0.f, 0.f, 0.f};
        #pragma unroll
        for (int i = 0; i < 32; ++i)
            __builtin_nontemporal_store(z, oz + zb + i * 128);
    }
    __syncthreads();

    // ---- C: reduce + transform (384 threads: r = tid/96, j = tid%96) ----
    if (tid < RPB * P3M) {
        const int r = tid / P3M, j = tid % P3M;
        float p = bias[j];
        #pragma unroll
        for (int kq = 0; kq < KQ; ++kq) p += sP[kq][r][j];
        const int m = j & 31;
        if (j < M_MIX) {
            sA[r][m] = __expf(p);
        } else if (j < 2 * M_MIX) {
            const float be = __expf(p);
            sC[r][m] = -be * 1.44269504f;
            sR[r][m] = 6.0827625f * __frsqrt_rn(be);   // sqrt(37/beta)
        } else {
            const float ka = prev_kappa[(size_t)(b0 + r) * M_MIX + m] + __expf(p);
            sK[r][m] = ka;
            out[(size_t)B_SZ * T_MAX + (size_t)(b0 + r) * M_MIX + m] = ka;
        }
    }
    __syncthreads();

    // ---- D: per-row window reduce; wave r handles row r ----
    if (tid < RPB * 64) {
        const int r = tid >> 6;
        const int m = tid & 31;     // mixtures duplicated across 64 lanes
        float lo = sK[r][m] - sR[r][m];
        float hi = sK[r][m] + sR[r][m];
        #pragma unroll
        for (int off = 32; off >= 1; off >>= 1) {
            lo = fminf(lo, __shfl_xor(lo, off));
            hi = fmaxf(hi, __shfl_xor(hi, off));
        }
        if ((tid & 63) == 0) { sRange[r][0] = lo; sRange[r][1] = hi; }
    }
    __syncthreads();

    // ---- E: phi, 2 passes x 2 rows; r = pass*2 + (tid>>8) ----
    const int   lt    = tid & 255;
    const int   wbase = lt & ~63;
    const float tf    = (float)lt;

    #pragma unroll
    for (int pass = 0; pass < 2; ++pass) {
        const int   r    = pass * 2 + (tid >> 8);
        const float gmin = sRange[r][0], gmax = sRange[r][1];

        float acc[16];
        #pragma unroll
        for (int i = 0; i < 16; ++i) acc[i] = 0.f;

        #pragma unroll
        for (int i = 0; i < 16; ++i) {
            const float wlo = (float)(wbase + i * 256);
            if (gmax >= wlo && gmin <= wlo + 63.0f) {   // wave-uniform skip
                const float t = tf + (float)(i * 256);
                #pragma unroll 4
                for (int m = 0; m < M_MIX; ++m) {
                    const float d = sK[r][m] - t;
                    acc[i] += sA[r][m] * exp2f(sC[r][m] * d * d);
                }
            }
        }

        // mask + per-thread sum
        const int L = sL[r];
        float s = 0.f;
        #pragma unroll
        for (int i = 0; i < 16; ++i) {
            const int t = lt + i * 256;
            if (t >= L) acc[i] = 0.f;
            s += acc[i];
        }
        #pragma unroll
        for (int off = 32; off >= 1; off >>= 1) s += __shfl_xor(s, off);
        if ((tid & 63) == 0) sRed[r][(tid >> 6) & 3] = s;
        __syncthreads();
        const float invn = 1.0f /
            (sRed[r][0] + sRed[r][1] + sRed[r][2] + sRed[r][3] + 1e-8f);

        // stores: only i-blocks intersecting [0, gmax]; rest zeroed in B
        int nI = __float2int_rz(gmax * (1.0f / 256.0f)) + 1;
        nI = (nI < 1) ? 1 : (nI > 16) ? 16 : nI;

        float* ob = out + (size_t)(b0 + r) * T_MAX;
        #pragma unroll
        for (int i = 0; i < 16; ++i)
            if (i < nI)
                __builtin_nontemporal_store(acc[i] * invn, ob + lt + i * 256);
    }
}

extern "C" void kernel_launch(void* const* d_in, const int* in_sizes, int n_in,
                              void* d_out, int out_size, void* d_ws, size_t ws_size,
                              hipStream_t stream) {
    const float* query = (const float*)d_in[0];
    const float* prevk = (const float*)d_in[1];
    const float* W     = (const float*)d_in[2];
    const float* bias  = (const float*)d_in[3];
    const int*   msl   = (const int*)d_in[4];
    float* out = (float*)d_out;
    (void)d_ws; (void)ws_size;

    fused_kernel<<<NBLK, NTHR, 0, stream>>>(query, prevk, W, bias, msl, out);
}